// Round 3
// baseline (507.791 us; speedup 1.0000x reference)
//
#include <hip/hip_runtime.h>
#include <hip/hip_cooperative_groups.h>
#include <math.h>

namespace cg = cooperative_groups;

#define NN   5000
#define INF_ 64
#define HID  32
#define NH   4
#define OUTF 64
#define NEG  0.2f
#define CAP  256   // max neighbors/row; E[deg]=101, max~150 -> safe margin

typedef float nt4 __attribute__((ext_vector_type(4)));  // native vector for nontemporal builtin

__device__ inline float wred_sum(float v) {
#pragma unroll
    for (int off = 32; off > 0; off >>= 1) v += __shfl_down(v, off, 64);
    return v;
}

__device__ inline unsigned mask4(nt4 v) {
    return (v.x > 0.f ? 1u : 0u) | (v.y > 0.f ? 2u : 0u) |
           (v.z > 0.f ? 4u : 0u) | (v.w > 0.f ? 8u : 0u);
}

// one LDS pool, phase-overlaid (max ~8.8 KB)
union alignas(16) SMem {
    struct { int nbs[CAP]; int wt4[4]; } p1;
    struct { int nb[CAP]; float sc[NH][CAP + 1]; float aggf[4][128];
             float xs[128]; float redh[4 * NH]; float pw[4][64]; } p2;
    struct { int nb[CAP]; float sc[CAP]; float red[4]; float agg[4][64]; } p3;
};

// ---------------- fused: k1 / grid.sync / k2 / grid.sync / k3 ----------------
// Same block handles the same rows in every phase (idx/counts stay L2-local).
// Phase bodies are the round-2 verified kernels; phase 3 widened to 4 waves.
__global__ __launch_bounds__(256) void fused(
        const float* __restrict__ adj, const float* __restrict__ h,
        const float* __restrict__ W1, const float* __restrict__ a1s,
        const float* __restrict__ a1d, const float* __restrict__ W2,
        const float* __restrict__ a2s, const float* __restrict__ a2d,
        float* __restrict__ out, float* __restrict__ Wh1, float* __restrict__ Wh2,
        float* __restrict__ s1s, float* __restrict__ s1d,
        float* __restrict__ s2s, float* __restrict__ s2d,
        int* __restrict__ counts, int* __restrict__ idx) {
    cg::grid_group gg = cg::this_grid();
    const int t = threadIdx.x, lane = t & 63, wave = t >> 6;
    __shared__ SMem sm;

    // ---------------- phase 1: Wh1 + scores + compacted neighbor list --------
    for (int i = blockIdx.x; i < NN; i += gridDim.x) {
        const nt4* row4 = (const nt4*)(adj + (size_t)i * NN);  // 1250 nt4 per row
        nt4 v0 = __builtin_nontemporal_load(&row4[t]);
        nt4 v1 = __builtin_nontemporal_load(&row4[t + 256]);
        nt4 v2 = __builtin_nontemporal_load(&row4[t + 512]);
        nt4 v3 = __builtin_nontemporal_load(&row4[t + 768]);
        nt4 v4 = {0.f, 0.f, 0.f, 0.f};
        if (t < NN / 4 - 1024) v4 = __builtin_nontemporal_load(&row4[t + 1024]);
        const float hreg = h[(size_t)i * INF_ + lane];   // full h row per wave
        // Wh1 row + scores (waves 0-1) overlap the in-flight adjacency loads
        if (t < 128) {
            float acc = 0.f;
#pragma unroll
            for (int k = 0; k < INF_; ++k) acc += __shfl(hreg, k, 64) * W1[k * (NH * HID) + t];
            Wh1[(size_t)i * (NH * HID) + t] = acc;
            const int hd = t >> 5, f = t & 31;
            float vs = acc * a1s[hd * HID + f];
            float vd = acc * a1d[hd * HID + f];
#pragma unroll
            for (int off = 16; off > 0; off >>= 1) {
                vs += __shfl_down(vs, off, 32);
                vd += __shfl_down(vd, off, 32);
            }
            if (f == 0) { s1s[i * NH + hd] = vs; s1d[i * NH + hd] = vd; }
        }
        // 20-bit presence mask per lane, single wave prefix-sum
        const unsigned m20 = mask4(v0) | (mask4(v1) << 4) | (mask4(v2) << 8) |
                             (mask4(v3) << 12) | (mask4(v4) << 16);
        const int cl = __popc(m20);
        int incl = cl;
#pragma unroll
        for (int off = 1; off < 64; off <<= 1) {
            int u = __shfl_up(incl, off, 64);
            if (lane >= off) incl += u;
        }
        if (lane == 63) sm.p1.wt4[wave] = incl;
        __syncthreads();
        int base = 0;
#pragma unroll
        for (int w = 0; w < 4; ++w) base += (w < wave) ? sm.p1.wt4[w] : 0;
        int p = base + (incl - cl);            // exclusive prefix within block
        unsigned m = m20;
        while (m) {
            const int b = __ffs(m) - 1; m &= m - 1;
            const int nid = 4 * (t + (b >> 2) * 256) + (b & 3);
            if (p < CAP) sm.p1.nbs[p] = nid;
            ++p;
        }
        __syncthreads();
        const int tot = sm.p1.wt4[0] + sm.p1.wt4[1] + sm.p1.wt4[2] + sm.p1.wt4[3];
        const int c = tot < CAP ? tot : CAP;
        if (t == 0) counts[i] = c;
        int4* my4 = (int4*)(idx + (size_t)i * CAP);
        for (int e = t; e < ((c + 3) >> 2); e += 256) my4[e] = ((const int4*)sm.p1.nbs)[e];
        __syncthreads();   // protect wt4/nbs for next grid-stride row
    }
    __threadfence();
    gg.sync();

    // ---------------- phase 2: layer-1 attention + ELU + Wh2 + scores --------
    for (int i = blockIdx.x; i < NN; i += gridDim.x) {
        const int c = counts[i];
        const int cp = (c + 3) & ~3;
        const float4 ss = ((const float4*)s1s)[i];
        const float4* s1d4 = (const float4*)s1d;
        const int* my = idx + (size_t)i * CAP;
        float l0 = 0.f, l1 = 0.f, l2 = 0.f, l3 = 0.f;
        for (int e = t; e < c; e += 256) {   // fused: load + score + exp + sum
            const int j = my[e];
            sm.p2.nb[e] = j;
            const float4 sd = s1d4[j];
            float w0 = ss.x + sd.x, w1 = ss.y + sd.y, w2 = ss.z + sd.z, w3 = ss.w + sd.w;
            w0 = (w0 >= 0.f) ? w0 : NEG * w0;
            w1 = (w1 >= 0.f) ? w1 : NEG * w1;
            w2 = (w2 >= 0.f) ? w2 : NEG * w2;
            w3 = (w3 >= 0.f) ? w3 : NEG * w3;
            const float p0 = __expf(w0), p1 = __expf(w1), p2 = __expf(w2), p3 = __expf(w3);
            sm.p2.sc[0][e] = p0; sm.p2.sc[1][e] = p1; sm.p2.sc[2][e] = p2; sm.p2.sc[3][e] = p3;
            l0 += p0; l1 += p1; l2 += p2; l3 += p3;
        }
        for (int e = c + t; e < cp; e += 256) {   // zero-pad: contributes 0
            sm.p2.nb[e] = 0;
            sm.p2.sc[0][e] = 0.f; sm.p2.sc[1][e] = 0.f; sm.p2.sc[2][e] = 0.f; sm.p2.sc[3][e] = 0.f;
        }
        l0 = wred_sum(l0); l1 = wred_sum(l1); l2 = wred_sum(l2); l3 = wred_sum(l3);
        if (lane == 0) {
            sm.p2.redh[wave * NH + 0] = l0; sm.p2.redh[wave * NH + 1] = l1;
            sm.p2.redh[wave * NH + 2] = l2; sm.p2.redh[wave * NH + 3] = l3;
        }
        __syncthreads();   // barrier 1
        {   // aggregate: lane halves cover 2 edges/instruction, x2 unroll
            const float4* Wh1v = (const float4*)Wh1;   // row j = 32 float4
            const int half = lane >> 5, fi = lane & 31, hd = fi >> 3;
            const int g4 = cp >> 2;
            const int gw = (g4 + 3) >> 2;
            int g = wave * gw;
            const int gend = min(g4, wave * gw + gw);
            float4 a0 = {0.f,0.f,0.f,0.f}, a1 = a0, a2 = a0, a3 = a0;
            for (; g + 1 < gend; g += 2) {
                const int e = 4 * g;
                const int j0 = sm.p2.nb[e + half],     j1 = sm.p2.nb[e + 2 + half];
                const int j2 = sm.p2.nb[e + 4 + half], j3 = sm.p2.nb[e + 6 + half];
                const float p0 = sm.p2.sc[hd][e + half],     p1 = sm.p2.sc[hd][e + 2 + half];
                const float p2 = sm.p2.sc[hd][e + 4 + half], p3 = sm.p2.sc[hd][e + 6 + half];
                const float4 w0 = Wh1v[(size_t)j0 * 32 + fi];
                const float4 w1 = Wh1v[(size_t)j1 * 32 + fi];
                const float4 w2 = Wh1v[(size_t)j2 * 32 + fi];
                const float4 w3 = Wh1v[(size_t)j3 * 32 + fi];
                a0.x += p0 * w0.x; a0.y += p0 * w0.y; a0.z += p0 * w0.z; a0.w += p0 * w0.w;
                a1.x += p1 * w1.x; a1.y += p1 * w1.y; a1.z += p1 * w1.z; a1.w += p1 * w1.w;
                a2.x += p2 * w2.x; a2.y += p2 * w2.y; a2.z += p2 * w2.z; a2.w += p2 * w2.w;
                a3.x += p3 * w3.x; a3.y += p3 * w3.y; a3.z += p3 * w3.z; a3.w += p3 * w3.w;
            }
            if (g < gend) {
                const int e = 4 * g;
                const int j0 = sm.p2.nb[e + half], j1 = sm.p2.nb[e + 2 + half];
                const float p0 = sm.p2.sc[hd][e + half], p1 = sm.p2.sc[hd][e + 2 + half];
                const float4 w0 = Wh1v[(size_t)j0 * 32 + fi];
                const float4 w1 = Wh1v[(size_t)j1 * 32 + fi];
                a0.x += p0 * w0.x; a0.y += p0 * w0.y; a0.z += p0 * w0.z; a0.w += p0 * w0.w;
                a1.x += p1 * w1.x; a1.y += p1 * w1.y; a1.z += p1 * w1.z; a1.w += p1 * w1.w;
            }
            float4 aa;
            aa.x = (a0.x + a1.x) + (a2.x + a3.x);
            aa.y = (a0.y + a1.y) + (a2.y + a3.y);
            aa.z = (a0.z + a1.z) + (a2.z + a3.z);
            aa.w = (a0.w + a1.w) + (a2.w + a3.w);
            aa.x += __shfl_xor(aa.x, 32, 64);
            aa.y += __shfl_xor(aa.y, 32, 64);
            aa.z += __shfl_xor(aa.z, 32, 64);
            aa.w += __shfl_xor(aa.w, 32, 64);
            if (lane < 32) ((float4*)sm.p2.aggf[wave])[lane] = aa;
        }
        __syncthreads();   // barrier 2
        if (t < 128) {
            const int hh = t >> 5;
            const float lh = sm.p2.redh[hh] + sm.p2.redh[NH + hh] +
                             sm.p2.redh[2 * NH + hh] + sm.p2.redh[3 * NH + hh];
            float o = sm.p2.aggf[0][t] + sm.p2.aggf[1][t] + sm.p2.aggf[2][t] + sm.p2.aggf[3][t];
            o = o / lh;
            o = (o > 0.f) ? o : expm1f(o);   // ELU
            sm.p2.xs[t] = o;
        }
        __syncthreads();   // barrier 3
        {   // Wh2 row: 4 k-chunks of 32 x 64 outputs
            float pa = 0.f;
#pragma unroll
            for (int k = 0; k < 32; ++k)
                pa += sm.p2.xs[wave * 32 + k] * W2[(wave * 32 + k) * OUTF + lane];
            sm.p2.pw[wave][lane] = pa;
        }
        __syncthreads();   // barrier 4
        if (t < 64) {
            float w = sm.p2.pw[0][t] + sm.p2.pw[1][t] + sm.p2.pw[2][t] + sm.p2.pw[3][t];
            Wh2[(size_t)i * OUTF + t] = w;
            float vs = wred_sum(w * a2s[t]);
            float vd = wred_sum(w * a2d[t]);
            if (t == 0) { s2s[i] = vs; s2d[i] = vd; }
        }
        // no trailing barrier needed: next row's first LDS writes (nb/sc) are
        // only read after its own barrier 1; all cross-row hazards are covered
    }
    __threadfence();
    gg.sync();

    // ---------------- phase 3: layer-2 attention -> out ----------------------
    for (int i = blockIdx.x; i < NN; i += gridDim.x) {
        const int c = counts[i];
        const int cp = (c + 3) & ~3;
        const float si = s2s[i];
        const int* my = idx + (size_t)i * CAP;
        float lsum = 0.f;
        for (int e = t; e < c; e += 256) {
            const int j = my[e];
            sm.p3.nb[e] = j;
            float v = si + s2d[j];
            v = (v >= 0.f) ? v : NEG * v;
            const float p = __expf(v);
            sm.p3.sc[e] = p;
            lsum += p;
        }
        for (int e = c + t; e < cp; e += 256) { sm.p3.nb[e] = 0; sm.p3.sc[e] = 0.f; }
        lsum = wred_sum(lsum);
        if (lane == 0) sm.p3.red[wave] = lsum;
        __syncthreads();   // barrier 1
        const float4* Wh2v = (const float4*)Wh2;   // row j = 16 float4
        const int qi = lane >> 4, fi = lane & 15;  // quarter-edge, float4 feature
        const int g4 = cp >> 2;
        const int gw = (g4 + 3) >> 2;
        int g = wave * gw;
        const int gend = min(g4, wave * gw + gw);
        float4 a0 = {0.f,0.f,0.f,0.f}, a1 = a0;
        for (; g + 1 < gend; g += 2) {
            const int eA = 4 * g + qi, eB = 4 * g + 4 + qi;
            const int jA = sm.p3.nb[eA], jB = sm.p3.nb[eB];
            const float pA = sm.p3.sc[eA], pB = sm.p3.sc[eB];
            const float4 wA = Wh2v[(size_t)jA * 16 + fi];
            const float4 wB = Wh2v[(size_t)jB * 16 + fi];
            a0.x += pA * wA.x; a0.y += pA * wA.y; a0.z += pA * wA.z; a0.w += pA * wA.w;
            a1.x += pB * wB.x; a1.y += pB * wB.y; a1.z += pB * wB.z; a1.w += pB * wB.w;
        }
        if (g < gend) {
            const int eA = 4 * g + qi;
            const int jA = sm.p3.nb[eA];
            const float pA = sm.p3.sc[eA];
            const float4 wA = Wh2v[(size_t)jA * 16 + fi];
            a0.x += pA * wA.x; a0.y += pA * wA.y; a0.z += pA * wA.z; a0.w += pA * wA.w;
        }
        float4 aa;
        aa.x = a0.x + a1.x; aa.y = a0.y + a1.y; aa.z = a0.z + a1.z; aa.w = a0.w + a1.w;
#pragma unroll
        for (int off = 16; off <= 32; off <<= 1) {
            aa.x += __shfl_xor(aa.x, off, 64);
            aa.y += __shfl_xor(aa.y, off, 64);
            aa.z += __shfl_xor(aa.z, off, 64);
            aa.w += __shfl_xor(aa.w, off, 64);
        }
        if (lane < 16) ((float4*)sm.p3.agg[wave])[lane] = aa;
        __syncthreads();   // barrier 2
        if (t < 64) {
            const float ls = sm.p3.red[0] + sm.p3.red[1] + sm.p3.red[2] + sm.p3.red[3];
            const float s = sm.p3.agg[0][t] + sm.p3.agg[1][t] + sm.p3.agg[2][t] + sm.p3.agg[3][t];
            out[(size_t)i * OUTF + t] = s / ls;
        }
        __syncthreads();   // protect red/agg for next grid-stride row
    }
}

extern "C" void kernel_launch(void* const* d_in, const int* in_sizes, int n_in,
                              void* d_out, int out_size, void* d_ws, size_t ws_size,
                              hipStream_t stream) {
    const float* adj = (const float*)d_in[0];
    const float* h   = (const float*)d_in[1];
    const float* W1  = (const float*)d_in[2];
    const float* a1s = (const float*)d_in[3];
    const float* a1d = (const float*)d_in[4];
    const float* W2  = (const float*)d_in[5];
    const float* a2s = (const float*)d_in[6];
    const float* a2d = (const float*)d_in[7];
    float* out = (float*)d_out;

    char* p = (char*)d_ws;
    float* Wh1 = (float*)p; p += (size_t)NN * 128 * 4;
    float* Wh2 = (float*)p; p += (size_t)NN * OUTF * 4;
    float* s1s = (float*)p; p += (size_t)NN * NH * 4;
    float* s1d = (float*)p; p += (size_t)NN * NH * 4;
    float* s2s = (float*)p; p += (size_t)NN * 4;
    float* s2d = (float*)p; p += (size_t)NN * 4;
    int*   cnt = (int*)p;   p += (size_t)NN * 4;
    int*   idx = (int*)p;   p += (size_t)NN * CAP * 4;

    static int grid = 0;
    if (grid == 0) {   // host-side queries only; graph-capture safe
        int dev = 0;
        hipGetDevice(&dev);
        hipDeviceProp_t prop;
        hipGetDeviceProperties(&prop, dev);
        int nb = 0;
        hipOccupancyMaxActiveBlocksPerMultiprocessor(&nb, fused, 256, 0);
        if (nb < 1) nb = 1;
        long g = (long)nb * prop.multiProcessorCount;
        if (g > NN) g = NN;
        grid = (int)g;
    }

    void* args[] = {
        (void*)&adj, (void*)&h, (void*)&W1, (void*)&a1s, (void*)&a1d,
        (void*)&W2, (void*)&a2s, (void*)&a2d, (void*)&out,
        (void*)&Wh1, (void*)&Wh2, (void*)&s1s, (void*)&s1d,
        (void*)&s2s, (void*)&s2d, (void*)&cnt, (void*)&idx
    };
    hipLaunchCooperativeKernel(fused, dim3(grid), dim3(256), args, 0, stream);
}

// Round 4
// 189.809 us; speedup vs baseline: 2.6753x; 2.6753x over previous
//
#include <hip/hip_runtime.h>
#include <math.h>

#define NN   5000
#define INF_ 64
#define HID  32
#define NH   4
#define OUTF 64
#define NEG  0.2f
#define CAP  256   // max neighbors/row; E[deg]=101, max~150 -> safe margin

typedef float nt4 __attribute__((ext_vector_type(4)));  // native vector for nontemporal builtin

__device__ inline float wred_sum(float v) {
#pragma unroll
    for (int off = 32; off > 0; off >>= 1) v += __shfl_down(v, off, 64);
    return v;
}

__device__ inline unsigned mask4(nt4 v) {
    return (v.x > 0.f ? 1u : 0u) | (v.y > 0.f ? 2u : 0u) |
           (v.z > 0.f ? 4u : 0u) | (v.w > 0.f ? 8u : 0u);
}

// ---------------- K1: Wh1 + layer-1 scores + compacted neighbor list ---------
// (verified round-2 body, unchanged)
__global__ __launch_bounds__(256) void k1(const float* __restrict__ adj,
        const float* __restrict__ h, const float* __restrict__ W1,
        const float* __restrict__ a1s, const float* __restrict__ a1d,
        int* __restrict__ counts, int* __restrict__ idx,
        float* __restrict__ Wh1, float* __restrict__ s1s, float* __restrict__ s1d) {
    const int i = blockIdx.x, t = threadIdx.x;
    const int lane = t & 63, wave = t >> 6;
    __shared__ int nbs[CAP];
    __shared__ int wt4[4];
    // decoupled streaming: all loads in flight before any consumption
    const nt4* row4 = (const nt4*)(adj + (size_t)i * NN);  // 1250 nt4 per row
    nt4 v0 = __builtin_nontemporal_load(&row4[t]);
    nt4 v1 = __builtin_nontemporal_load(&row4[t + 256]);
    nt4 v2 = __builtin_nontemporal_load(&row4[t + 512]);
    nt4 v3 = __builtin_nontemporal_load(&row4[t + 768]);
    nt4 v4 = {0.f, 0.f, 0.f, 0.f};
    if (t < NN / 4 - 1024) v4 = __builtin_nontemporal_load(&row4[t + 1024]);
    const float hreg = h[(size_t)i * INF_ + lane];   // each wave holds full h row
    // Wh1 row + scores (waves 0-1) overlap with the in-flight adjacency loads
    if (t < 128) {
        float acc = 0.f;
#pragma unroll
        for (int k = 0; k < INF_; ++k) acc += __shfl(hreg, k, 64) * W1[k * (NH * HID) + t];
        Wh1[(size_t)i * (NH * HID) + t] = acc;
        const int hd = t >> 5, f = t & 31;
        float vs = acc * a1s[hd * HID + f];
        float vd = acc * a1d[hd * HID + f];
#pragma unroll
        for (int off = 16; off > 0; off >>= 1) {
            vs += __shfl_down(vs, off, 32);
            vd += __shfl_down(vd, off, 32);
        }
        if (f == 0) { s1s[i * NH + hd] = vs; s1d[i * NH + hd] = vd; }
    }
    // 20-bit presence mask per lane, single wave prefix-sum
    const unsigned m20 = mask4(v0) | (mask4(v1) << 4) | (mask4(v2) << 8) |
                         (mask4(v3) << 12) | (mask4(v4) << 16);
    const int cl = __popc(m20);
    int incl = cl;
#pragma unroll
    for (int off = 1; off < 64; off <<= 1) {
        int u = __shfl_up(incl, off, 64);
        if (lane >= off) incl += u;
    }
    if (lane == 63) wt4[wave] = incl;     // per-wave total (race-free slot)
    __syncthreads();                       // all loads consumed by now: drain is free
    int base = 0;
#pragma unroll
    for (int w = 0; w < 4; ++w) base += (w < wave) ? wt4[w] : 0;
    int p = base + (incl - cl);            // exclusive prefix within block
    unsigned m = m20;
    while (m) {
        const int b = __ffs(m) - 1; m &= m - 1;
        const int nid = 4 * (t + (b >> 2) * 256) + (b & 3);
        if (p < CAP) nbs[p] = nid;
        ++p;
    }
    __syncthreads();
    const int tot = wt4[0] + wt4[1] + wt4[2] + wt4[3];
    const int c = tot < CAP ? tot : CAP;
    if (t == 0) counts[i] = c;
    int4* my4 = (int4*)(idx + (size_t)i * CAP);
    for (int e = t; e < ((c + 3) >> 2); e += 256) my4[e] = ((const int4*)nbs)[e];
}

// ---------------- K2: layer-1 attention + ELU + Wh2 + layer-2 scores ---------
// Change vs round 2: each wave scores ITS OWN edge chunk then aggregates it
// immediately -- wave-private LDS handoff needs no __syncthreads (lgkmcnt
// ordering suffices). Denominator reduction deferred off the critical path.
__global__ __launch_bounds__(256) void k2(const int* __restrict__ counts,
        const int* __restrict__ idx, const float* __restrict__ Wh1,
        const float* __restrict__ s1s, const float* __restrict__ s1d,
        const float* __restrict__ W2, const float* __restrict__ a2s,
        const float* __restrict__ a2d, float* __restrict__ Wh2,
        float* __restrict__ s2s, float* __restrict__ s2d) {
    const int i = blockIdx.x, t = threadIdx.x;
    const int lane = t & 63, wave = t >> 6;
    const int c = counts[i];
    const int cp = (c + 3) & ~3;
    __shared__ int   nb[CAP];
    __shared__ float sc[NH][CAP + 1];   // +1: de-alias banks for per-head reads
    __shared__ float aggf[4][128];
    __shared__ float xs[128];
    __shared__ float redh[4 * NH];
    __shared__ float pw[4][64];
    const float4 ss = ((const float4*)s1s)[i];
    const float4* s1d4 = (const float4*)s1d;
    const int* my = idx + (size_t)i * CAP;
    // per-wave edge chunk (multiple of 4 edges)
    const int g4 = cp >> 2;                    // 4-edge groups total
    const int gw = (g4 + 3) >> 2;              // groups per wave
    const int ge0 = wave * gw * 4;             // first edge of this wave's chunk
    const int ge1 = min(cp, ge0 + gw * 4);     // padded end
    float l0 = 0.f, l1 = 0.f, l2 = 0.f, l3 = 0.f;
    // score own chunk: load + score + exp + partial sum (+ zero-pad tail)
    for (int e = ge0 + lane; e < ge1; e += 64) {
        if (e < c) {
            const int j = my[e];
            nb[e] = j;
            const float4 sd = s1d4[j];
            float w0 = ss.x + sd.x, w1 = ss.y + sd.y, w2 = ss.z + sd.z, w3 = ss.w + sd.w;
            w0 = (w0 >= 0.f) ? w0 : NEG * w0;
            w1 = (w1 >= 0.f) ? w1 : NEG * w1;
            w2 = (w2 >= 0.f) ? w2 : NEG * w2;
            w3 = (w3 >= 0.f) ? w3 : NEG * w3;
            const float p0 = __expf(w0), p1 = __expf(w1), p2 = __expf(w2), p3 = __expf(w3);
            sc[0][e] = p0; sc[1][e] = p1; sc[2][e] = p2; sc[3][e] = p3;
            l0 += p0; l1 += p1; l2 += p2; l3 += p3;
        } else {   // zero-pad: contributes exactly 0
            nb[e] = 0;
            sc[0][e] = 0.f; sc[1][e] = 0.f; sc[2][e] = 0.f; sc[3][e] = 0.f;
        }
    }
    // aggregate own chunk immediately (reads only own-wave nb/sc slice)
    {
        const float4* Wh1v = (const float4*)Wh1;   // row j = 32 float4
        const int half = lane >> 5, fi = lane & 31, hd = fi >> 3;
        int g = wave * gw;
        const int gend = min(g4, wave * gw + gw);
        float4 a0 = {0.f,0.f,0.f,0.f}, a1 = a0, a2 = a0, a3 = a0;
        for (; g + 1 < gend; g += 2) {
            const int e = 4 * g;
            const int j0 = nb[e + half],     j1 = nb[e + 2 + half];
            const int j2 = nb[e + 4 + half], j3 = nb[e + 6 + half];
            const float p0 = sc[hd][e + half],     p1 = sc[hd][e + 2 + half];
            const float p2 = sc[hd][e + 4 + half], p3 = sc[hd][e + 6 + half];
            const float4 w0 = Wh1v[(size_t)j0 * 32 + fi];
            const float4 w1 = Wh1v[(size_t)j1 * 32 + fi];
            const float4 w2 = Wh1v[(size_t)j2 * 32 + fi];
            const float4 w3 = Wh1v[(size_t)j3 * 32 + fi];
            a0.x += p0 * w0.x; a0.y += p0 * w0.y; a0.z += p0 * w0.z; a0.w += p0 * w0.w;
            a1.x += p1 * w1.x; a1.y += p1 * w1.y; a1.z += p1 * w1.z; a1.w += p1 * w1.w;
            a2.x += p2 * w2.x; a2.y += p2 * w2.y; a2.z += p2 * w2.z; a2.w += p2 * w2.w;
            a3.x += p3 * w3.x; a3.y += p3 * w3.y; a3.z += p3 * w3.z; a3.w += p3 * w3.w;
        }
        if (g < gend) {
            const int e = 4 * g;
            const int j0 = nb[e + half], j1 = nb[e + 2 + half];
            const float p0 = sc[hd][e + half], p1 = sc[hd][e + 2 + half];
            const float4 w0 = Wh1v[(size_t)j0 * 32 + fi];
            const float4 w1 = Wh1v[(size_t)j1 * 32 + fi];
            a0.x += p0 * w0.x; a0.y += p0 * w0.y; a0.z += p0 * w0.z; a0.w += p0 * w0.w;
            a1.x += p1 * w1.x; a1.y += p1 * w1.y; a1.z += p1 * w1.z; a1.w += p1 * w1.w;
        }
        float4 aa;
        aa.x = (a0.x + a1.x) + (a2.x + a3.x);
        aa.y = (a0.y + a1.y) + (a2.y + a3.y);
        aa.z = (a0.z + a1.z) + (a2.z + a3.z);
        aa.w = (a0.w + a1.w) + (a2.w + a3.w);
        aa.x += __shfl_xor(aa.x, 32, 64);
        aa.y += __shfl_xor(aa.y, 32, 64);
        aa.z += __shfl_xor(aa.z, 32, 64);
        aa.w += __shfl_xor(aa.w, 32, 64);
        if (lane < 32) ((float4*)aggf[wave])[lane] = aa;
    }
    // denominator reduction off the critical path (consumed after barrier 1)
    l0 = wred_sum(l0); l1 = wred_sum(l1); l2 = wred_sum(l2); l3 = wred_sum(l3);
    if (lane == 0) {
        redh[wave * NH + 0] = l0; redh[wave * NH + 1] = l1;
        redh[wave * NH + 2] = l2; redh[wave * NH + 3] = l3;
    }
    __syncthreads();   // barrier 1: aggf + redh ready
    if (t < 128) {
        const int hh = t >> 5;
        const float lh = redh[hh] + redh[NH + hh] + redh[2 * NH + hh] + redh[3 * NH + hh];
        float o = aggf[0][t] + aggf[1][t] + aggf[2][t] + aggf[3][t];
        o = o / lh;
        o = (o > 0.f) ? o : expm1f(o);   // ELU
        xs[t] = o;
    }
    __syncthreads();   // barrier 2
    // Wh2 row: 4 k-chunks of 32 x 64 outputs
    {
        float pa = 0.f;
#pragma unroll
        for (int k = 0; k < 32; ++k)
            pa += xs[wave * 32 + k] * W2[(wave * 32 + k) * OUTF + lane];
        pw[wave][lane] = pa;
    }
    __syncthreads();   // barrier 3
    if (t < 64) {
        float w = pw[0][t] + pw[1][t] + pw[2][t] + pw[3][t];
        Wh2[(size_t)i * OUTF + t] = w;
        float vs = wred_sum(w * a2s[t]);
        float vd = wred_sum(w * a2d[t]);
        if (t == 0) { s2s[i] = vs; s2d[i] = vd; }
    }
}

// ---------------- K3: layer-2 attention -> d_out -----------------------------
// Change vs round 2: per-wave chunk scored + aggregated end-to-end, single
// barrier; denominator reduction deferred.
__global__ __launch_bounds__(128) void k3(const int* __restrict__ counts,
        const int* __restrict__ idx, const float* __restrict__ Wh2,
        const float* __restrict__ s2s, const float* __restrict__ s2d,
        float* __restrict__ out) {
    const int i = blockIdx.x, t = threadIdx.x;
    const int lane = t & 63, wave = t >> 6;
    const int c = counts[i];
    const int cp = (c + 3) & ~3;
    __shared__ int   nb[CAP];
    __shared__ float sc[CAP];
    __shared__ float red[2];
    __shared__ float agg[2][64];
    const float si = s2s[i];
    const int* my = idx + (size_t)i * CAP;
    const int g4 = cp >> 2;                    // 4-edge groups total
    const int gw = (g4 + 1) >> 1;              // groups per wave
    const int ge0 = wave * gw * 4;
    const int ge1 = min(cp, ge0 + gw * 4);
    float lsum = 0.f;
    for (int e = ge0 + lane; e < ge1; e += 64) {
        if (e < c) {
            const int j = my[e];
            nb[e] = j;
            float v = si + s2d[j];
            v = (v >= 0.f) ? v : NEG * v;
            const float p = __expf(v);
            sc[e] = p;
            lsum += p;
        } else { nb[e] = 0; sc[e] = 0.f; }
    }
    // aggregate own chunk immediately (no barrier; own-wave LDS slice only)
    const float4* Wh2v = (const float4*)Wh2;   // row j = 16 float4
    const int qi = lane >> 4, fi = lane & 15;  // quarter-edge, float4 feature
    int g = wave * gw;
    const int gend = min(g4, wave * gw + gw);
    float4 a0 = {0.f,0.f,0.f,0.f}, a1 = a0;
    for (; g + 1 < gend; g += 2) {
        const int eA = 4 * g + qi, eB = 4 * g + 4 + qi;
        const int jA = nb[eA], jB = nb[eB];
        const float pA = sc[eA], pB = sc[eB];
        const float4 wA = Wh2v[(size_t)jA * 16 + fi];
        const float4 wB = Wh2v[(size_t)jB * 16 + fi];
        a0.x += pA * wA.x; a0.y += pA * wA.y; a0.z += pA * wA.z; a0.w += pA * wA.w;
        a1.x += pB * wB.x; a1.y += pB * wB.y; a1.z += pB * wB.z; a1.w += pB * wB.w;
    }
    if (g < gend) {
        const int eA = 4 * g + qi;
        const int jA = nb[eA];
        const float pA = sc[eA];
        const float4 wA = Wh2v[(size_t)jA * 16 + fi];
        a0.x += pA * wA.x; a0.y += pA * wA.y; a0.z += pA * wA.z; a0.w += pA * wA.w;
    }
    float4 aa;
    aa.x = a0.x + a1.x; aa.y = a0.y + a1.y; aa.z = a0.z + a1.z; aa.w = a0.w + a1.w;
#pragma unroll
    for (int off = 16; off <= 32; off <<= 1) {
        aa.x += __shfl_xor(aa.x, off, 64);
        aa.y += __shfl_xor(aa.y, off, 64);
        aa.z += __shfl_xor(aa.z, off, 64);
        aa.w += __shfl_xor(aa.w, off, 64);
    }
    if (lane < 16) ((float4*)agg[wave])[lane] = aa;
    lsum = wred_sum(lsum);                     // off the critical path
    if (lane == 0) red[wave] = lsum;
    __syncthreads();   // single barrier
    if (t < 64) {
        const float ls = red[0] + red[1];
        const float s = agg[0][t] + agg[1][t];
        out[(size_t)i * OUTF + t] = s / ls;
    }
}

extern "C" void kernel_launch(void* const* d_in, const int* in_sizes, int n_in,
                              void* d_out, int out_size, void* d_ws, size_t ws_size,
                              hipStream_t stream) {
    const float* adj = (const float*)d_in[0];
    const float* h   = (const float*)d_in[1];
    const float* W1  = (const float*)d_in[2];
    const float* a1s = (const float*)d_in[3];
    const float* a1d = (const float*)d_in[4];
    const float* W2  = (const float*)d_in[5];
    const float* a2s = (const float*)d_in[6];
    const float* a2d = (const float*)d_in[7];
    float* out = (float*)d_out;

    char* p = (char*)d_ws;
    float* Wh1 = (float*)p; p += (size_t)NN * 128 * 4;
    float* Wh2 = (float*)p; p += (size_t)NN * OUTF * 4;
    float* s1s = (float*)p; p += (size_t)NN * NH * 4;
    float* s1d = (float*)p; p += (size_t)NN * NH * 4;
    float* s2s = (float*)p; p += (size_t)NN * 4;
    float* s2d = (float*)p; p += (size_t)NN * 4;
    int*   cnt = (int*)p;   p += (size_t)NN * 4;
    int*   idx = (int*)p;   p += (size_t)NN * CAP * 4;

    k1<<<NN, 256, 0, stream>>>(adj, h, W1, a1s, a1d, cnt, idx, Wh1, s1s, s1d);
    k2<<<NN, 256, 0, stream>>>(cnt, idx, Wh1, s1s, s1d, W2, a2s, a2d, Wh2, s2s, s2d);
    k3<<<NN, 128, 0, stream>>>(cnt, idx, Wh2, s2s, s2d, out);
}